// Round 5
// baseline (679.783 us; speedup 1.0000x reference)
//
#include <hip/hip_runtime.h>
#include <hip/hip_cooperative_groups.h>
#include <math.h>

namespace cg = cooperative_groups;

#define N1 16384
#define N2 4096
#define DIM 256
#define ATT 128

typedef unsigned int uint32;
typedef __attribute__((ext_vector_type(4))) short s4v;
typedef __attribute__((ext_vector_type(8))) short s8v;
typedef __attribute__((ext_vector_type(16))) float f16v;
typedef __attribute__((ext_vector_type(2))) uint32 u2v;
typedef __attribute__((ext_vector_type(4))) uint32 u4v;

union S8U { s8v v; s4v h[2]; };

#define AS1C const __attribute__((address_space(1)))
#define AS3 __attribute__((address_space(3)))

// ---- workspace layout (float offsets) ----
#define WS_KPK 0              // K frag-packed bf16  [4096*256] = 2MB
#define WS_VPK 524288         // V^T frag-packed bf16
#define WS_WQT 1048576        // packed weight frags, 128KB each (256x256)
#define WS_WOT 1081344
#define WS_W1T 1114112
#define WS_WKT 1146880
#define WS_WVT 1179648
#define WS_W2T 1212416
#define WS_VAT 1245184        // 64KB (256x128)
#define WS_UAT 1261568
#define WS_ACC 1277952        // zeroed: colsum1,colsum2,s2sum,pooled (1024 f)
#define WS_COLSUM1 (WS_ACC)
#define WS_COLSUM2 (WS_ACC+256)
#define WS_S2SUM  (WS_ACC+512)
#define WS_POOLED (WS_ACC+768)
#define WS_ALOGIT (WS_ACC+1024)     // [4096]
#define WS_AW     (WS_ALOGIT+4096)  // [4096]
#define WS_CVEC   (WS_AW+4096)      // [256]
#define WS_GATE   (WS_CVEC+256)     // [8]

// ---- flash LDS layout (bytes): K 64K | V 64K | P 16K | misc ----
#define L_K    0
#define L_V    65536
#define L_P    131072
#define L_LP   147456
#define L_LINV 149504
#define L_RRS  149760
#define L_RR   150016
#define L_X1PK  0          // prologue alias (K region, 32 KB)
#define L_QPAD  65536      // prologue alias (V region, 33 KB)
#define L_OBUF  0          // epilogue alias (K region, 32 KB)
#define L_X1PK2 65536      // epilogue alias (V region, 32 KB)
#define SMEM_BYTES 150272

__device__ __forceinline__ uint32 f2bf1(float f) {
    uint32 u = __float_as_uint(f);
    return (u + 0x7fffu + ((u >> 16) & 1u)) >> 16;
}
__device__ __forceinline__ uint32 f2bf2(float lo, float hi) {
    return f2bf1(lo) | (f2bf1(hi) << 16);
}
#define MFMA32(a, b, c) __builtin_amdgcn_mfma_f32_32x32x16_bf16((a), (b), (c), 0, 0, 0)

__global__ __launch_bounds__(512, 2) void k_all(
    const float* __restrict__ x1, const float* __restrict__ x2,
    const float* __restrict__ sim, const float* __restrict__ gates,
    const float* __restrict__ g1, const float* __restrict__ g2,
    const float* __restrict__ snn_w1, const float* __restrict__ b1,
    const float* __restrict__ snn_w2, const float* __restrict__ b2,
    const float* __restrict__ wq, const float* __restrict__ wk,
    const float* __restrict__ wv, const float* __restrict__ wo,
    const float* __restrict__ va, const float* __restrict__ ua,
    const float* __restrict__ wa, const float* __restrict__ wf,
    float* __restrict__ ws, float* __restrict__ out)
{
    extern __shared__ char sm[];
    cg::grid_group grid = cg::this_grid();
    const int t = threadIdx.x;
    const int b = blockIdx.x;
    const int w = t >> 6;
    const int lane = t & 63;
    const int l31 = lane & 31;
    const int lh = lane >> 5;

    // ================= P0: zero accumulators =================
    if (b == 0) {
        for (int i = t; i < 1024; i += 512) ws[WS_ACC + i] = 0.f;
    }
    __threadfence();
    grid.sync();

    // ================= P1: weight packing (t<256) + colsums (t>=256) ========
    if (t < 256) {
        if (b < 224) {
            int mat, chunk, ncols;
            if (b < 192) { mat = b >> 5; chunk = b & 31; ncols = 256; }
            else { mat = 6 + ((b - 192) >> 4); chunk = (b - 192) & 15; ncols = 128; }
            const float* W;
            int dstoff;
            switch (mat) {
                case 0: W = wq;     dstoff = WS_WQT; break;
                case 1: W = wo;     dstoff = WS_WOT; break;
                case 2: W = snn_w1; dstoff = WS_W1T; break;
                case 3: W = wk;     dstoff = WS_WKT; break;
                case 4: W = wv;     dstoff = WS_WVT; break;
                case 5: W = snn_w2; dstoff = WS_W2T; break;
                case 6: W = va;     dstoff = WS_VAT; break;
                default: W = ua;    dstoff = WS_UAT; break;
            }
            unsigned short* dst = (unsigned short*)(ws + dstoff);
            const int e0 = chunk * 2048 + t * 8;
            const int k = (ncols == 256) ? (e0 >> 8) : (e0 >> 7);
            const int n0 = (ncols == 256) ? (e0 & 255) : (e0 & 127);
            const float4 v0 = *(const float4*)(W + k * ncols + n0);
            const float4 v1 = *(const float4*)(W + k * ncols + n0 + 4);
            const float sc = (mat == 2) ? g1[k] : ((mat == 5) ? g2[k] : 1.0f);
            float vals[8] = {v0.x, v0.y, v0.z, v0.w, v1.x, v1.y, v1.z, v1.w};
            const unsigned int sbase = (unsigned int)(k >> 4) * 512u
                + 32u * ((k >> 3) & 1) * 8u + (k & 7);
            #pragma unroll
            for (int jj = 0; jj < 8; ++jj) {
                const int n = n0 + jj;
                unsigned int off = (unsigned int)(n >> 5) * 16u * 512u + sbase
                                 + (unsigned int)(n & 31) * 8u;
                dst[off] = (unsigned short)f2bf1(vals[jj] * sc);
            }
        }
    } else {
        const int col = t - 256;
        float acc = 0.f;
        for (int r = 0; r < 64; ++r) acc += x1[(size_t)(b * 64 + r) * DIM + col];
        atomicAdd(&ws[WS_COLSUM1 + col], acc);
        if (b < 64) {
            float a2 = 0.f;
            for (int r = 0; r < 64; ++r) a2 += x2[(size_t)(b * 64 + r) * DIM + col];
            atomicAdd(&ws[WS_COLSUM2 + col], a2);
        }
    }
    __threadfence();
    grid.sync();

    // ================= P2: x2 prep via MFMA (blocks 0..127) =================
    if (b < 128) {
        char* xps = sm;                         // 16 KB x2^T frags
        float* rrs = (float*)(sm + 16384);      // 32 f
        float* dlp = (float*)(sm + 16512);      // 4 x 32 f
        const int tb = b * 32;
        unsigned short* kpk = (unsigned short*)(ws + WS_KPK);
        unsigned short* vpk = (unsigned short*)(ws + WS_VPK);
        const char* wsb = (const char*)ws;
        const char* wkt = wsb + (size_t)WS_WKT * 4;
        const char* wvt = wsb + (size_t)WS_WVT * 4;
        const char* w2t = wsb + (size_t)WS_W2T * 4;
        const char* vat = wsb + (size_t)WS_VAT * 4;
        const char* uat = wsb + (size_t)WS_UAT * 4;

        #pragma unroll
        for (int i = 0; i < 2; ++i) {
            const int c = t + 512 * i;
            const int tk = c >> 5, d0 = (c & 31) * 8;
            const float4 a = *(const float4*)(x2 + (size_t)(tb + tk) * DIM + d0);
            const float4 bb = *(const float4*)(x2 + (size_t)(tb + tk) * DIM + d0 + 4);
            float ss = a.x*a.x + a.y*a.y + a.z*a.z + a.w*a.w
                     + bb.x*bb.x + bb.y*bb.y + bb.z*bb.z + bb.w*bb.w;
            #pragma unroll
            for (int o = 16; o > 0; o >>= 1) ss += __shfl_down(ss, o, 32);
            if ((t & 31) == 0) rrs[tk] = ss;
            u4v pk;
            pk.x = f2bf2(a.x, a.y); pk.y = f2bf2(a.z, a.w);
            pk.z = f2bf2(bb.x, bb.y); pk.w = f2bf2(bb.z, bb.w);
            *(u4v*)(xps + (d0 >> 4) * 1024 + (tk + 32 * ((d0 >> 3) & 1)) * 16) = pk;
        }
        __syncthreads();

        { // K^T = wk^T * x2^T
            f16v kacc = (f16v)0.0f;
            #pragma unroll
            for (int s = 0; s < 16; ++s) {
                const s8v a = *(const s8v*)(wkt + (w * 16 + s) * 1024 + lane * 16);
                const s8v bb = *(const s8v*)(xps + s * 1024 + lane * 16);
                kacc = MFMA32(a, bb, kacc);
            }
            #pragma unroll
            for (int g = 0; g < 4; ++g) {
                const unsigned int chunkK =
                    (unsigned int)((b >> 1) * 32 + 2 * (2 * w + (g >> 1)) + (b & 1));
                const unsigned int off = chunkK * 512u
                    + (unsigned int)(l31 + 32 * (g & 1)) * 8u + 4u * lh;
                u2v pk;
                pk.x = f2bf2(kacc[4 * g + 0], kacc[4 * g + 1]);
                pk.y = f2bf2(kacc[4 * g + 2], kacc[4 * g + 3]);
                *(u2v*)(kpk + off) = pk;
            }
        }
        { // V = x2 * wv
            f16v vacc = (f16v)0.0f;
            #pragma unroll
            for (int s = 0; s < 16; ++s) {
                const s8v a = *(const s8v*)(xps + s * 1024 + lane * 16);
                const s8v bb = *(const s8v*)(wvt + (w * 16 + s) * 1024 + lane * 16);
                vacc = MFMA32(a, bb, vacc);
            }
            #pragma unroll
            for (int g = 0; g < 4; ++g) {
                const unsigned int chunkV =
                    (unsigned int)((b >> 1) * 32 + 4 * w + 2 * (b & 1) + (g >> 1));
                const unsigned int off = chunkV * 512u
                    + (unsigned int)(l31 + 32 * (g & 1)) * 8u + 4u * lh;
                u2v pk;
                pk.x = f2bf2(vacc[4 * g + 0], vacc[4 * g + 1]);
                pk.y = f2bf2(vacc[4 * g + 2], vacc[4 * g + 3]);
                *(u2v*)(vpk + off) = pk;
            }
        }
        { // SNN elu colsum -> S2SUM
            f16v sacc = (f16v)0.0f;
            #pragma unroll
            for (int s = 0; s < 16; ++s) {
                const s8v a = *(const s8v*)(w2t + (w * 16 + s) * 1024 + lane * 16);
                const s8v bb = *(const s8v*)(xps + s * 1024 + lane * 16);
                sacc = MFMA32(a, bb, sacc);
            }
            const float rrl = rsqrtf(rrs[l31] * (1.0f / DIM) + 1e-6f);
            #pragma unroll
            for (int g = 0; g < 4; ++g) {
                const float4 bb = *(const float4*)(b2 + 32 * w + 8 * g + 4 * lh);
                #pragma unroll
                for (int jj = 0; jj < 4; ++jj) {
                    float v = sacc[4 * g + jj] * rrl + ((const float*)&bb)[jj];
                    v = (v > 0.f) ? v : expm1f(v);
                    v += __shfl_xor(v, 16); v += __shfl_xor(v, 8);
                    v += __shfl_xor(v, 4);  v += __shfl_xor(v, 2);
                    v += __shfl_xor(v, 1);
                    if (l31 == 0)
                        atomicAdd(&ws[WS_S2SUM + 32 * w + 8 * g + 4 * lh + jj], v);
                }
            }
        }
        if (w < 4) { // DAMISL logits
            f16v hv = (f16v)0.0f, hu = (f16v)0.0f;
            #pragma unroll
            for (int s = 0; s < 16; ++s) {
                const s8v bb = *(const s8v*)(xps + s * 1024 + lane * 16);
                const s8v a1 = *(const s8v*)(vat + (w * 16 + s) * 1024 + lane * 16);
                const s8v a2 = *(const s8v*)(uat + (w * 16 + s) * 1024 + lane * 16);
                hv = MFMA32(a1, bb, hv);
                hu = MFMA32(a2, bb, hu);
            }
            float acc = 0.f;
            #pragma unroll
            for (int g = 0; g < 4; ++g) {
                const float4 w4 = *(const float4*)(wa + 32 * w + 8 * g + 4 * lh);
                #pragma unroll
                for (int jj = 0; jj < 4; ++jj) {
                    acc += tanhf(hv[4 * g + jj])
                         * (1.0f / (1.0f + expf(-hu[4 * g + jj])))
                         * ((const float*)&w4)[jj];
                }
            }
            acc += __shfl_xor(acc, 32);
            if (lh == 0) dlp[w * 32 + l31] = acc;
        }
        __syncthreads();
        if (t < 32)
            ws[WS_ALOGIT + tb + t] = dlp[t] + dlp[32 + t] + dlp[64 + t] + dlp[96 + t];
    }
    __threadfence();
    grid.sync();

    // ================= P3: gate + DAMISL softmax (block 0) =================
    if (b == 0) {
        float* red  = (float*)sm;           // 512 f
        float* acc9 = (float*)(sm + 2048);  // 9 f
        if (t < 9) acc9[t] = 0.f;
        __syncthreads();
        float fv = 0.f;
        if (t < 256)
            fv = 0.5f * (ws[WS_COLSUM1 + t] * (1.0f / N1)
                       + ws[WS_COLSUM2 + t] * (1.0f / N2));
        {
            float p = fv * fv;
            #pragma unroll
            for (int o = 32; o > 0; o >>= 1) p += __shfl_xor(p, o);
            if (lane == 0) atomicAdd(&acc9[0], p);
        }
        #pragma unroll
        for (int e = 0; e < 4; ++e) {
            const float sv = (t < 256) ? sim[e * DIM + t] : 0.f;
            float pn = sv * sv, pd = sv * fv;
            #pragma unroll
            for (int o = 32; o > 0; o >>= 1) { pn += __shfl_xor(pn, o); pd += __shfl_xor(pd, o); }
            if (lane == 0) { atomicAdd(&acc9[1 + e], pn); atomicAdd(&acc9[5 + e], pd); }
        }
        __syncthreads();
        if (t == 0) {
            const float rsqf = rsqrtf(acc9[0] + 1e-8f);
            float sc[4];
            #pragma unroll
            for (int e = 0; e < 4; ++e)
                sc[e] = acc9[5 + e] * rsqf * rsqrtf(acc9[1 + e] + 1e-8f);
            float a = -1e30f, bb = -1e30f;
            #pragma unroll
            for (int e = 0; e < 4; ++e) {
                const float v = sc[e];
                if (v > a) { bb = a; a = v; } else if (v > bb) { bb = v; }
            }
            float wv_[4]; int ns = 0;
            #pragma unroll
            for (int e = 0; e < 4; ++e) {
                const bool keep = (sc[e] >= bb) && (sc[e] > gates[e]);
                wv_[e] = keep ? sc[e] : 0.f;
                if (wv_[e] > 0.f) ns++;
            }
            if (ns < 1) ns = 1;
            ws[WS_GATE + 0] = wv_[0]; ws[WS_GATE + 1] = wv_[1];
            ws[WS_GATE + 2] = wv_[2]; ws[WS_GATE + 3] = wv_[3];
            ws[WS_GATE + 4] = 1.0f / (float)ns;
            ws[WS_GATE + 5] = wv_[0] + wv_[2] + wv_[3];
        }
        // DAMISL softmax over ALOGIT[4096]
        float mx = -1e30f;
        for (int i = t; i < N2; i += 512) mx = fmaxf(mx, ws[WS_ALOGIT + i]);
        red[t] = mx; __syncthreads();
        for (int s = 256; s > 0; s >>= 1) {
            if (t < s) red[t] = fmaxf(red[t], red[t + s]);
            __syncthreads();
        }
        mx = red[0]; __syncthreads();
        float sum = 0.f;
        for (int i = t; i < N2; i += 512) {
            const float e_ = __expf(ws[WS_ALOGIT + i] - mx);
            ws[WS_AW + i] = e_;
            sum += e_;
        }
        red[t] = sum; __syncthreads();
        for (int s = 256; s > 0; s >>= 1) {
            if (t < s) red[t] += red[t + s];
            __syncthreads();
        }
        const float is = 1.0f / red[0];
        for (int i = t; i < N2; i += 512) ws[WS_AW + i] *= is;
    }
    __threadfence();
    grid.sync();

    // ================= P4: pooled = a^T x2 (blocks 0..127) =================
    if (b < 128) {
        const int col = t & 255, rh = t >> 8;
        const int r0 = b * 32 + rh * 16;
        float acc = 0.f;
        for (int r = 0; r < 16; ++r)
            acc = fmaf(ws[WS_AW + r0 + r], x2[(size_t)(r0 + r) * DIM + col], acc);
        atomicAdd(&ws[WS_POOLED + col], acc);
    }
    __threadfence();
    grid.sync();

    // ================= P5: cvec (block 0) =================
    if (b == 0) {
        float* pl = (float*)sm;
        if (t < 256) pl[t] = ws[WS_POOLED + t];
        __syncthreads();
        if (t < 256) {
            float acc = 0.f;
            for (int k = 0; k < 256; ++k) acc = fmaf(pl[k], wf[k * DIM + t], acc);
            ws[WS_CVEC + t] = ws[WS_GATE + 1] * (ws[WS_S2SUM + t] * (1.0f / N2))
                            + ws[WS_GATE + 2] * acc;
        }
    }
    __threadfence();
    grid.sync();

    // ================= P6: flash attention + fused epilogue (all blocks) ====
    {
        const int qb = b * 64;
        const int kh = w >> 1, qh = w & 1;     // S-phase roles
        const int qp = w & 1, dpair = w >> 1;  // PV-phase roles
        const char* wsb = (const char*)ws;
        const char* kpk = wsb + (size_t)WS_KPK * 4;
        const char* vpk = wsb + (size_t)WS_VPK * 4;
        const char* wqt = wsb + (size_t)WS_WQT * 4;
        const char* wot = wsb + (size_t)WS_WOT * 4;
        const char* w1t = wsb + (size_t)WS_W1T * 4;

        auto stage64 = [&](const char* gbase, int ldsoff) {
            #pragma unroll
            for (int i = 0; i < 8; ++i) {
                const int c = w * 8 + i;
                __builtin_amdgcn_global_load_lds(
                    (AS1C uint32*)(gbase + c * 1024 + lane * 16),
                    (AS3 uint32*)(sm + ldsoff + c * 1024), 16, 0, 0);
            }
        };

        // ---- prologue: x1 frags + rms partials
        #pragma unroll
        for (int i = 0; i < 4; ++i) {
            const int c = t + 512 * i;
            const int q = c >> 5, d0 = (c & 31) * 8;
            const float4 a = *(const float4*)(x1 + (size_t)(qb + q) * DIM + d0);
            const float4 bb = *(const float4*)(x1 + (size_t)(qb + q) * DIM + d0 + 4);
            float ss = a.x*a.x + a.y*a.y + a.z*a.z + a.w*a.w
                     + bb.x*bb.x + bb.y*bb.y + bb.z*bb.z + bb.w*bb.w;
            #pragma unroll
            for (int o = 16; o > 0; o >>= 1) ss += __shfl_down(ss, o, 32);
            if ((t & 31) == 0) *(float*)(sm + L_RRS + q * 4) = ss;
            u4v pk;
            pk.x = f2bf2(a.x, a.y); pk.y = f2bf2(a.z, a.w);
            pk.z = f2bf2(bb.x, bb.y); pk.w = f2bf2(bb.z, bb.w);
            *(u4v*)(sm + L_X1PK + ((q >> 5) * 16 + (d0 >> 4)) * 1024
                    + ((q & 31) + 32 * ((d0 >> 3) & 1)) * 16) = pk;
        }
        __syncthreads();
        if (t < 64) {
            const float s2 = *(const float*)(sm + L_RRS + t * 4);
            *(float*)(sm + L_RR + t * 4) = rsqrtf(s2 * (1.0f / DIM) + 1e-6f);
        }
        // ---- Q^T = wq^T * x1^T -> QPAD
        #pragma unroll
        for (int i = 0; i < 2; ++i) {
            const int mt = w, qt = i;
            f16v qa = (f16v)0.0f;
            #pragma unroll
            for (int s = 0; s < 16; ++s) {
                const s8v a  = *(const s8v*)(wqt + (mt * 16 + s) * 1024 + lane * 16);
                const s8v bb = *(const s8v*)(sm + L_X1PK + (qt * 16 + s) * 1024 + lane * 16);
                qa = MFMA32(a, bb, qa);
            }
            const int q = qt * 32 + l31;
            #pragma unroll
            for (int g = 0; g < 4; ++g) {
                const int d0 = 32 * mt + 8 * g + 4 * lh;
                u2v pk;
                pk.x = f2bf2(qa[4 * g + 0], qa[4 * g + 1]);
                pk.y = f2bf2(qa[4 * g + 2], qa[4 * g + 3]);
                *(u2v*)(sm + L_QPAD + q * 520 + d0 * 2) = pk;
            }
        }
        __syncthreads();
        // ---- Q B-frags into regs
        s8v qf[16];
        {
            const char* qbase = sm + L_QPAD + (qh * 32 + l31) * 520 + lh * 16;
            #pragma unroll
            for (int s = 0; s < 16; ++s) {
                S8U u;
                u.h[0] = *(const s4v*)(qbase + s * 32);
                u.h[1] = *(const s4v*)(qbase + s * 32 + 8);
                qf[s] = u.v;
            }
        }
        stage64(kpk, L_K);
        __syncthreads();   // drain K(0); QPAD reads complete

        f16v oacc0 = (f16v)0.0f, oacc1 = (f16v)0.0f;
        float lsum = 0.0f;

        for (int tile = 0; tile < 32; ++tile) {
            stage64(vpk + (size_t)tile * 65536, L_V);
            f16v sacc = (f16v)0.0f;
            #pragma unroll
            for (int s = 0; s < 16; ++s) {
                const s8v a = *(const s8v*)(sm + L_K
                    + ((kh >> 1) * 32 + 2 * s + (kh & 1)) * 1024 + lane * 16);
                sacc = MFMA32(a, qf[s], sacc);
            }
            #pragma unroll
            for (int g = 0; g < 4; ++g) {
                const float p0 = __expf(sacc[4 * g + 0] * 0.0625f);
                const float p1 = __expf(sacc[4 * g + 1] * 0.0625f);
                const float p2 = __expf(sacc[4 * g + 2] * 0.0625f);
                const float p3 = __expf(sacc[4 * g + 3] * 0.0625f);
                lsum += (p0 + p1) + (p2 + p3);
                const int keyo = 32 * kh + 8 * g + 4 * lh;
                const int kc = keyo >> 4, ko = keyo & 15;
                u2v pk; pk.x = f2bf2(p0, p1); pk.y = f2bf2(p2, p3);
                *(u2v*)(sm + L_P + (qh * 8 + kc) * 1024
                        + (l31 + 32 * (ko >> 3)) * 16 + (ko & 7) * 2) = pk;
            }
            __syncthreads();   // barrier A: drains V(tile); P visible
            if (tile < 31) stage64(kpk + (size_t)(tile + 1) * 65536, L_K);
            s8v pf[8];
            #pragma unroll
            for (int kc = 0; kc < 8; ++kc)
                pf[kc] = *(const s8v*)(sm + L_P + (qp * 8 + kc) * 1024 + lane * 16);
            #pragma unroll
            for (int kc = 0; kc < 8; ++kc) {
                const int sub = (kc >> 2) * 32, k3 = kc & 3;
                const s8v a0 = *(const s8v*)(sm + L_V + (sub + 4 * (2 * dpair) + k3) * 1024 + lane * 16);
                const s8v a1 = *(const s8v*)(sm + L_V + (sub + 4 * (2 * dpair + 1) + k3) * 1024 + lane * 16);
                oacc0 = MFMA32(a0, pf[kc], oacc0);
                oacc1 = MFMA32(a1, pf[kc], oacc1);
            }
            __syncthreads();   // barrier B: drains K(tile+1)
        }

        // ---- softmax denominators
        *(float*)(sm + L_LP + ((w * 2 + lh) * 32 + l31) * 4) = lsum;
        __syncthreads();
        if (t < 64) {
            const int qh_ = t >> 5, c = t & 31;
            const float* lp = (const float*)(sm + L_LP);
            float l = 0.f;
            #pragma unroll
            for (int k2 = 0; k2 < 4; ++k2)
                l += lp[((k2 * 2 + qh_) * 2 + 0) * 32 + c]
                   + lp[((k2 * 2 + qh_) * 2 + 1) * 32 + c];
            *(float*)(sm + L_LINV + t * 4) = 1.0f / l;
        }
        __syncthreads();
        // ---- pack Ohat = O/l into OBUF
        {
            const float li = *(const float*)(sm + L_LINV + (qp * 32 + l31) * 4);
            #pragma unroll
            for (int half = 0; half < 2; ++half) {
                const f16v acc = half ? oacc1 : oacc0;
                const int dc = 2 * dpair + half;
                #pragma unroll
                for (int g = 0; g < 4; ++g) {
                    const int d0 = dc * 32 + 8 * g + 4 * lh;
                    u2v pk;
                    pk.x = f2bf2(acc[4 * g + 0] * li, acc[4 * g + 1] * li);
                    pk.y = f2bf2(acc[4 * g + 2] * li, acc[4 * g + 3] * li);
                    *(u2v*)(sm + L_OBUF + (qp * 16 + (d0 >> 4)) * 1024
                            + (l31 + 32 * ((d0 >> 3) & 1)) * 16 + (d0 & 7) * 2) = pk;
                }
            }
        }
        // ---- rebuild x1 frags
        #pragma unroll
        for (int i = 0; i < 4; ++i) {
            const int c = t + 512 * i;
            const int q = c >> 5, d0 = (c & 31) * 8;
            const float4 a = *(const float4*)(x1 + (size_t)(qb + q) * DIM + d0);
            const float4 bb = *(const float4*)(x1 + (size_t)(qb + q) * DIM + d0 + 4);
            u4v pk;
            pk.x = f2bf2(a.x, a.y); pk.y = f2bf2(a.z, a.w);
            pk.z = f2bf2(bb.x, bb.y); pk.w = f2bf2(bb.z, bb.w);
            *(u4v*)(sm + L_X1PK2 + ((q >> 5) * 16 + (d0 >> 4)) * 1024
                    + ((q & 31) + 32 * ((d0 >> 3) & 1)) * 16) = pk;
        }
        __syncthreads();
        // ---- combine + write out
        const float gw0 = ws[WS_GATE + 0], gw1 = ws[WS_GATE + 1];
        const float ginv = ws[WS_GATE + 4], gcx1 = ws[WS_GATE + 5];
        #pragma unroll
        for (int i = 0; i < 2; ++i) {
            const int mt = w, qt = i;
            f16v ea = (f16v)0.0f, sa = (f16v)0.0f;
            for (int s = 0; s < 16; ++s) {
                const s8v awo = *(const s8v*)(wot + (mt * 16 + s) * 1024 + lane * 16);
                const s8v aw1 = *(const s8v*)(w1t + (mt * 16 + s) * 1024 + lane * 16);
                const s8v bo = *(const s8v*)(sm + L_OBUF + (qt * 16 + s) * 1024 + lane * 16);
                const s8v bx = *(const s8v*)(sm + L_X1PK2 + (qt * 16 + s) * 1024 + lane * 16);
                ea = MFMA32(awo, bo, ea);
                sa = MFMA32(aw1, bx, sa);
            }
            const int q = qt * 32 + l31;
            const float rrq = *(const float*)(sm + L_RR + q * 4);
            #pragma unroll
            for (int g = 0; g < 4; ++g) {
                const int d0 = 32 * mt + 8 * g + 4 * lh;
                const float4 cv = *(const float4*)(ws + WS_CVEC + d0);
                const float4 bb = *(const float4*)(b1 + d0);
                const float4 xx = *(const float4*)(x1 + (size_t)(qb + q) * DIM + d0);
                float ev0 = sa[4 * g + 0] * rrq + bb.x; ev0 = (ev0 > 0.f) ? ev0 : expm1f(ev0);
                float ev1 = sa[4 * g + 1] * rrq + bb.y; ev1 = (ev1 > 0.f) ? ev1 : expm1f(ev1);
                float ev2 = sa[4 * g + 2] * rrq + bb.z; ev2 = (ev2 > 0.f) ? ev2 : expm1f(ev2);
                float ev3 = sa[4 * g + 3] * rrq + bb.w; ev3 = (ev3 > 0.f) ? ev3 : expm1f(ev3);
                float4 o;
                o.x = ginv * (gcx1 * xx.x + gw0 * ea[4 * g + 0] + gw1 * ev0 + cv.x);
                o.y = ginv * (gcx1 * xx.y + gw0 * ea[4 * g + 1] + gw1 * ev1 + cv.y);
                o.z = ginv * (gcx1 * xx.z + gw0 * ea[4 * g + 2] + gw1 * ev2 + cv.z);
                o.w = ginv * (gcx1 * xx.w + gw0 * ea[4 * g + 3] + gw1 * ev3 + cv.w);
                *(float4*)(out + (size_t)(qb + q) * DIM + d0) = o;
            }
        }
    }
}

extern "C" void kernel_launch(void* const* d_in, const int* in_sizes, int n_in,
                              void* d_out, int out_size, void* d_ws, size_t ws_size,
                              hipStream_t stream)
{
    (void)in_sizes; (void)n_in; (void)out_size; (void)ws_size;
    const float* x1    = (const float*)d_in[0];
    const float* x2    = (const float*)d_in[1];
    const float* sim   = (const float*)d_in[2];
    const float* gates = (const float*)d_in[3];
    const float* g1    = (const float*)d_in[4];
    const float* g2    = (const float*)d_in[5];
    const float* w1m   = (const float*)d_in[6];
    const float* b1    = (const float*)d_in[7];
    const float* w2m   = (const float*)d_in[8];
    const float* b2    = (const float*)d_in[9];
    const float* wq    = (const float*)d_in[10];
    const float* wk    = (const float*)d_in[11];
    const float* wv    = (const float*)d_in[12];
    const float* wo    = (const float*)d_in[13];
    const float* va    = (const float*)d_in[14];
    const float* ua    = (const float*)d_in[15];
    const float* wa    = (const float*)d_in[16];
    const float* wf    = (const float*)d_in[17];
    float* ws  = (float*)d_ws;
    float* out = (float*)d_out;

    void* args[20] = {
        (void*)&x1, (void*)&x2, (void*)&sim, (void*)&gates,
        (void*)&g1, (void*)&g2, (void*)&w1m, (void*)&b1,
        (void*)&w2m, (void*)&b2, (void*)&wq, (void*)&wk,
        (void*)&wv, (void*)&wo, (void*)&va, (void*)&ua,
        (void*)&wa, (void*)&wf, (void*)&ws, (void*)&out
    };
    hipLaunchCooperativeKernel((const void*)k_all, dim3(256), dim3(512),
                               args, SMEM_BYTES, stream);
}

// Round 6
// 251.095 us; speedup vs baseline: 2.7073x; 2.7073x over previous
//
#include <hip/hip_runtime.h>
#include <math.h>

#define N1 16384
#define N2 4096
#define DIM 256
#define ATT 128

typedef unsigned int uint32;
typedef __attribute__((ext_vector_type(4))) short s4v;
typedef __attribute__((ext_vector_type(8))) short s8v;
typedef __attribute__((ext_vector_type(16))) float f16v;
typedef __attribute__((ext_vector_type(2))) uint32 u2v;
typedef __attribute__((ext_vector_type(4))) uint32 u4v;

union S8U { s8v v; s4v h[2]; };

#define AS1C const __attribute__((address_space(1)))
#define AS3 __attribute__((address_space(3)))

// ---- workspace layout (float offsets) ----
#define WS_KPK 0              // K frag-packed bf16  [4096*256] = 2MB
#define WS_VPK 524288         // V^T frag-packed bf16
#define WS_WQT 1048576        // packed weight frags, 128KB each (256x256)
#define WS_WOT 1081344
#define WS_W1T 1114112
#define WS_WKT 1146880
#define WS_WVT 1179648
#define WS_W2T 1212416
#define WS_VAT 1245184        // 64KB (256x128)
#define WS_UAT 1261568
#define WS_ACC 1277952        // zeroed region (1056 floats)
#define WS_COLSUM1 (WS_ACC)
#define WS_COLSUM2 (WS_ACC+256)
#define WS_S2SUM  (WS_ACC+512)
#define WS_POOLED (WS_ACC+768)      // unnormalized: sum_i e_i * x2[i,:]
#define WS_SUME   (WS_ACC+1024)     // sum_i e_i
#define WS_GATE   (WS_ACC+1040)     // [8]: w0,w1,w2,w3,inv_ns,cx1

// ---- flash LDS layout (bytes): K 64K | V 64K | P 16K | misc ----
#define L_K    0
#define L_V    65536
#define L_P    131072
#define L_LP   147456
#define L_LINV 149504
#define L_RRS  149760
#define L_RR   150016
#define L_CVL  150272      // cvec [256 f]
#define L_X1PK  0          // prologue alias (K region, 32 KB)
#define L_QPAD  65536      // prologue alias (V region, 33 KB)
#define L_OBUF  0          // epilogue alias (K region, 32 KB)
#define L_X1PK2 65536      // epilogue alias (V region, 32 KB)
#define SMEM_BYTES 151296

__device__ __forceinline__ uint32 f2bf1(float f) {
    uint32 u = __float_as_uint(f);
    return (u + 0x7fffu + ((u >> 16) & 1u)) >> 16;
}
__device__ __forceinline__ uint32 f2bf2(float lo, float hi) {
    return f2bf1(lo) | (f2bf1(hi) << 16);
}
#define MFMA32(a, b, c) __builtin_amdgcn_mfma_f32_32x32x16_bf16((a), (b), (c), 0, 0, 0)

// ============ k_pre: wpack (blocks 0..223) | colsum1 (224..479) | colsum2 (480..543)
__global__ __launch_bounds__(256) void k_pre(const float* __restrict__ x1,
    const float* __restrict__ x2,
    const float* __restrict__ wq, const float* __restrict__ wo,
    const float* __restrict__ snn_w1, const float* __restrict__ wk,
    const float* __restrict__ wv, const float* __restrict__ snn_w2,
    const float* __restrict__ va, const float* __restrict__ ua,
    const float* __restrict__ g1, const float* __restrict__ g2,
    float* __restrict__ ws)
{
    const int b = blockIdx.x;
    const int t = threadIdx.x;
    if (b < 224) {
        int mat, chunk, ncols;
        if (b < 192) { mat = b >> 5; chunk = b & 31; ncols = 256; }
        else { mat = 6 + ((b - 192) >> 4); chunk = (b - 192) & 15; ncols = 128; }
        const float* W;
        int dstoff;
        switch (mat) {
            case 0: W = wq;     dstoff = WS_WQT; break;
            case 1: W = wo;     dstoff = WS_WOT; break;
            case 2: W = snn_w1; dstoff = WS_W1T; break;
            case 3: W = wk;     dstoff = WS_WKT; break;
            case 4: W = wv;     dstoff = WS_WVT; break;
            case 5: W = snn_w2; dstoff = WS_W2T; break;
            case 6: W = va;     dstoff = WS_VAT; break;
            default: W = ua;    dstoff = WS_UAT; break;
        }
        unsigned short* dst = (unsigned short*)(ws + dstoff);
        const int e0 = chunk * 2048 + t * 8;
        const int k = (ncols == 256) ? (e0 >> 8) : (e0 >> 7);
        const int n0 = (ncols == 256) ? (e0 & 255) : (e0 & 127);
        const float4 v0 = *(const float4*)(W + k * ncols + n0);
        const float4 v1 = *(const float4*)(W + k * ncols + n0 + 4);
        const float sc = (mat == 2) ? g1[k] : ((mat == 5) ? g2[k] : 1.0f);
        float vals[8] = {v0.x, v0.y, v0.z, v0.w, v1.x, v1.y, v1.z, v1.w};
        const unsigned int sbase = (unsigned int)(k >> 4) * 512u
            + 32u * ((k >> 3) & 1) * 8u + (k & 7);
        #pragma unroll
        for (int jj = 0; jj < 8; ++jj) {
            const int n = n0 + jj;
            unsigned int off = (unsigned int)(n >> 5) * 16u * 512u + sbase
                             + (unsigned int)(n & 31) * 8u;
            dst[off] = (unsigned short)f2bf1(vals[jj] * sc);
        }
    } else if (b < 480) {
        const int rbase = (b - 224) * 64;
        float acc = 0.f;
        for (int r = 0; r < 64; ++r) acc += x1[(size_t)(rbase + r) * DIM + t];
        atomicAdd(&ws[WS_COLSUM1 + t], acc);
    } else {
        const int rbase = (b - 480) * 64;
        float acc = 0.f;
        for (int r = 0; r < 64; ++r) acc += x2[(size_t)(rbase + r) * DIM + t];
        atomicAdd(&ws[WS_COLSUM2 + t], acc);
    }
}

// ============ k_mid: x2prep via MFMA + expE/pooled partials (0..127) | gate (128)
__global__ __launch_bounds__(512) void k_mid(const float* __restrict__ x2,
    const float* __restrict__ b2, const float* __restrict__ wa,
    const float* __restrict__ sim, const float* __restrict__ gates,
    float* __restrict__ ws)
{
    __shared__ char xps[16384];     // x2^T frags
    __shared__ float rrs[32];
    __shared__ float dlp[128];
    __shared__ float expE[32];
    __shared__ float acc9[9];
    const int t = threadIdx.x;
    const int w = t >> 6;
    const int lane = t & 63;
    const int l31 = lane & 31;
    const int lh = lane >> 5;
    const int b = blockIdx.x;

    if (b == 128) {
        // ---- gate: cosine scores + top-2 + threshold
        if (t < 9) acc9[t] = 0.f;
        __syncthreads();
        float fv = 0.f;
        if (t < 256)
            fv = 0.5f * (ws[WS_COLSUM1 + t] * (1.0f / N1)
                       + ws[WS_COLSUM2 + t] * (1.0f / N2));
        {
            float p = fv * fv;
            #pragma unroll
            for (int o = 32; o > 0; o >>= 1) p += __shfl_xor(p, o);
            if (lane == 0) atomicAdd(&acc9[0], p);
        }
        #pragma unroll
        for (int e = 0; e < 4; ++e) {
            const float sv = (t < 256) ? sim[e * DIM + t] : 0.f;
            float pn = sv * sv, pd = sv * fv;
            #pragma unroll
            for (int o = 32; o > 0; o >>= 1) { pn += __shfl_xor(pn, o); pd += __shfl_xor(pd, o); }
            if (lane == 0) { atomicAdd(&acc9[1 + e], pn); atomicAdd(&acc9[5 + e], pd); }
        }
        __syncthreads();
        if (t == 0) {
            const float rsqf = rsqrtf(acc9[0] + 1e-8f);
            float sc[4];
            #pragma unroll
            for (int e = 0; e < 4; ++e)
                sc[e] = acc9[5 + e] * rsqf * rsqrtf(acc9[1 + e] + 1e-8f);
            float a = -1e30f, bb = -1e30f;
            #pragma unroll
            for (int e = 0; e < 4; ++e) {
                const float v = sc[e];
                if (v > a) { bb = a; a = v; } else if (v > bb) { bb = v; }
            }
            float wv_[4]; int ns = 0;
            #pragma unroll
            for (int e = 0; e < 4; ++e) {
                const bool keep = (sc[e] >= bb) && (sc[e] > gates[e]);
                wv_[e] = keep ? sc[e] : 0.f;
                if (wv_[e] > 0.f) ns++;
            }
            if (ns < 1) ns = 1;
            ws[WS_GATE + 0] = wv_[0]; ws[WS_GATE + 1] = wv_[1];
            ws[WS_GATE + 2] = wv_[2]; ws[WS_GATE + 3] = wv_[3];
            ws[WS_GATE + 4] = 1.0f / (float)ns;
            ws[WS_GATE + 5] = wv_[0] + wv_[2] + wv_[3];
        }
        return;
    }

    const int tb = b * 32;
    unsigned short* kpk = (unsigned short*)(ws + WS_KPK);
    unsigned short* vpk = (unsigned short*)(ws + WS_VPK);
    const char* wsb = (const char*)ws;
    const char* wkt = wsb + (size_t)WS_WKT * 4;
    const char* wvt = wsb + (size_t)WS_WVT * 4;
    const char* w2t = wsb + (size_t)WS_W2T * 4;
    const char* vat = wsb + (size_t)WS_VAT * 4;
    const char* uat = wsb + (size_t)WS_UAT * 4;

    // ---- load + pack x2 tile, rms partials
    #pragma unroll
    for (int i = 0; i < 2; ++i) {
        const int c = t + 512 * i;
        const int tk = c >> 5, d0 = (c & 31) * 8;
        const float4 a = *(const float4*)(x2 + (size_t)(tb + tk) * DIM + d0);
        const float4 bb = *(const float4*)(x2 + (size_t)(tb + tk) * DIM + d0 + 4);
        float ss = a.x*a.x + a.y*a.y + a.z*a.z + a.w*a.w
                 + bb.x*bb.x + bb.y*bb.y + bb.z*bb.z + bb.w*bb.w;
        #pragma unroll
        for (int o = 16; o > 0; o >>= 1) ss += __shfl_down(ss, o, 32);
        if ((t & 31) == 0) rrs[tk] = ss;
        u4v pk;
        pk.x = f2bf2(a.x, a.y); pk.y = f2bf2(a.z, a.w);
        pk.z = f2bf2(bb.x, bb.y); pk.w = f2bf2(bb.z, bb.w);
        *(u4v*)(xps + (d0 >> 4) * 1024 + (tk + 32 * ((d0 >> 3) & 1)) * 16) = pk;
    }
    __syncthreads();

    { // K^T = wk^T * x2^T
        f16v kacc = (f16v)0.0f;
        #pragma unroll
        for (int s = 0; s < 16; ++s) {
            const s8v a = *(const s8v*)(wkt + (w * 16 + s) * 1024 + lane * 16);
            const s8v bb = *(const s8v*)(xps + s * 1024 + lane * 16);
            kacc = MFMA32(a, bb, kacc);
        }
        #pragma unroll
        for (int g = 0; g < 4; ++g) {
            const unsigned int chunkK =
                (unsigned int)((b >> 1) * 32 + 2 * (2 * w + (g >> 1)) + (b & 1));
            const unsigned int off = chunkK * 512u
                + (unsigned int)(l31 + 32 * (g & 1)) * 8u + 4u * lh;
            u2v pk;
            pk.x = f2bf2(kacc[4 * g + 0], kacc[4 * g + 1]);
            pk.y = f2bf2(kacc[4 * g + 2], kacc[4 * g + 3]);
            *(u2v*)(kpk + off) = pk;
        }
    }
    { // V = x2 * wv
        f16v vacc = (f16v)0.0f;
        #pragma unroll
        for (int s = 0; s < 16; ++s) {
            const s8v a = *(const s8v*)(xps + s * 1024 + lane * 16);
            const s8v bb = *(const s8v*)(wvt + (w * 16 + s) * 1024 + lane * 16);
            vacc = MFMA32(a, bb, vacc);
        }
        #pragma unroll
        for (int g = 0; g < 4; ++g) {
            const unsigned int chunkV =
                (unsigned int)((b >> 1) * 32 + 4 * w + 2 * (b & 1) + (g >> 1));
            const unsigned int off = chunkV * 512u
                + (unsigned int)(l31 + 32 * (g & 1)) * 8u + 4u * lh;
            u2v pk;
            pk.x = f2bf2(vacc[4 * g + 0], vacc[4 * g + 1]);
            pk.y = f2bf2(vacc[4 * g + 2], vacc[4 * g + 3]);
            *(u2v*)(vpk + off) = pk;
        }
    }
    { // SNN elu colsum -> S2SUM
        f16v sacc = (f16v)0.0f;
        #pragma unroll
        for (int s = 0; s < 16; ++s) {
            const s8v a = *(const s8v*)(w2t + (w * 16 + s) * 1024 + lane * 16);
            const s8v bb = *(const s8v*)(xps + s * 1024 + lane * 16);
            sacc = MFMA32(a, bb, sacc);
        }
        const float rrl = rsqrtf(rrs[l31] * (1.0f / DIM) + 1e-6f);
        #pragma unroll
        for (int g = 0; g < 4; ++g) {
            const float4 bb = *(const float4*)(b2 + 32 * w + 8 * g + 4 * lh);
            #pragma unroll
            for (int jj = 0; jj < 4; ++jj) {
                float v = sacc[4 * g + jj] * rrl + ((const float*)&bb)[jj];
                v = (v > 0.f) ? v : expm1f(v);
                v += __shfl_xor(v, 16); v += __shfl_xor(v, 8);
                v += __shfl_xor(v, 4);  v += __shfl_xor(v, 2);
                v += __shfl_xor(v, 1);
                if (l31 == 0)
                    atomicAdd(&ws[WS_S2SUM + 32 * w + 8 * g + 4 * lh + jj], v);
            }
        }
    }
    if (w < 4) { // DAMISL logit partials over ATT chunk w
        f16v hv = (f16v)0.0f, hu = (f16v)0.0f;
        #pragma unroll
        for (int s = 0; s < 16; ++s) {
            const s8v bb = *(const s8v*)(xps + s * 1024 + lane * 16);
            const s8v a1 = *(const s8v*)(vat + (w * 16 + s) * 1024 + lane * 16);
            const s8v a2 = *(const s8v*)(uat + (w * 16 + s) * 1024 + lane * 16);
            hv = MFMA32(a1, bb, hv);
            hu = MFMA32(a2, bb, hu);
        }
        float acc = 0.f;
        #pragma unroll
        for (int g = 0; g < 4; ++g) {
            const float4 w4 = *(const float4*)(wa + 32 * w + 8 * g + 4 * lh);
            #pragma unroll
            for (int jj = 0; jj < 4; ++jj) {
                acc += tanhf(hv[4 * g + jj])
                     * (1.0f / (1.0f + expf(-hu[4 * g + jj])))
                     * ((const float*)&w4)[jj];
            }
        }
        acc += __shfl_xor(acc, 32);
        if (lh == 0) dlp[w * 32 + l31] = acc;
    }
    __syncthreads();
    if (t < 32) { // token logits -> expE (max-free; logits bounded) + sumE partial
        const float lg = dlp[t] + dlp[32 + t] + dlp[64 + t] + dlp[96 + t];
        const float e_ = __expf(lg);
        expE[t] = e_;
        float s = e_;
        #pragma unroll
        for (int o = 16; o > 0; o >>= 1) s += __shfl_xor(s, o);
        if (t == 0) atomicAdd(&ws[WS_SUME], s);
    }
    __syncthreads();
    { // pooledU partials: d = t&255, rows split by t>>8
        const int d = t & 255, half = t >> 8;
        const int r0 = half * 16;
        float acc = 0.f;
        #pragma unroll
        for (int r = 0; r < 16; ++r)
            acc = fmaf(expE[r0 + r], x2[(size_t)(tb + r0 + r) * DIM + d], acc);
        atomicAdd(&ws[WS_POOLED + d], acc);
    }
}

// ============ k_flash: MFMA flash attention + cvec preamble + fused epilogue
__global__ __launch_bounds__(512, 2) void k_flash(
    const float* __restrict__ x1, const float* __restrict__ b1,
    const float* __restrict__ wf,
    const float* __restrict__ wsf, float* __restrict__ out)
{
    extern __shared__ char sm[];
    const int t = threadIdx.x;
    const int w = t >> 6;
    const int lane = t & 63;
    const int l31 = lane & 31;
    const int lh = lane >> 5;
    const int qb = blockIdx.x * 64;
    const int kh = w >> 1, qh = w & 1;     // S-phase roles
    const int qp = w & 1, dpair = w >> 1;  // PV-phase roles
    const char* wsb = (const char*)wsf;
    const char* kpk = wsb + (size_t)WS_KPK * 4;
    const char* vpk = wsb + (size_t)WS_VPK * 4;
    const char* wqt = wsb + (size_t)WS_WQT * 4;
    const char* wot = wsb + (size_t)WS_WOT * 4;
    const char* w1t = wsb + (size_t)WS_W1T * 4;

    auto stage64 = [&](const char* gbase, int ldsoff) {
        #pragma unroll
        for (int i = 0; i < 8; ++i) {
            const int c = w * 8 + i;
            __builtin_amdgcn_global_load_lds(
                (AS1C uint32*)(gbase + c * 1024 + lane * 16),
                (AS3 uint32*)(sm + ldsoff + c * 1024), 16, 0, 0);
        }
    };

    // ---- cvec preamble: cvec = w1*s2mean + w2*((pooledU/sumE)@wf)
    if (t < 256) {
        const float se = wsf[WS_SUME];
        ((float*)(sm + L_LP))[t] = wsf[WS_POOLED + t] / se;
    }
    __syncthreads();
    if (t < 256) {
        const float* pl = (const float*)(sm + L_LP);
        float acc = 0.f;
        for (int k = 0; k < 256; ++k) acc = fmaf(pl[k], wf[k * DIM + t], acc);
        ((float*)(sm + L_CVL))[t] = wsf[WS_GATE + 1] * (wsf[WS_S2SUM + t] * (1.0f / N2))
                                  + wsf[WS_GATE + 2] * acc;
    }

    // ---- prologue: x1 frags + rms partials
    #pragma unroll
    for (int i = 0; i < 4; ++i) {
        const int c = t + 512 * i;
        const int q = c >> 5, d0 = (c & 31) * 8;
        const float4 a = *(const float4*)(x1 + (size_t)(qb + q) * DIM + d0);
        const float4 bb = *(const float4*)(x1 + (size_t)(qb + q) * DIM + d0 + 4);
        float ss = a.x*a.x + a.y*a.y + a.z*a.z + a.w*a.w
                 + bb.x*bb.x + bb.y*bb.y + bb.z*bb.z + bb.w*bb.w;
        #pragma unroll
        for (int o = 16; o > 0; o >>= 1) ss += __shfl_down(ss, o, 32);
        if ((t & 31) == 0) *(float*)(sm + L_RRS + q * 4) = ss;
        u4v pk;
        pk.x = f2bf2(a.x, a.y); pk.y = f2bf2(a.z, a.w);
        pk.z = f2bf2(bb.x, bb.y); pk.w = f2bf2(bb.z, bb.w);
        *(u4v*)(sm + L_X1PK + ((q >> 5) * 16 + (d0 >> 4)) * 1024
                + ((q & 31) + 32 * ((d0 >> 3) & 1)) * 16) = pk;
    }
    __syncthreads();
    if (t < 64) {
        const float s2 = *(const float*)(sm + L_RRS + t * 4);
        *(float*)(sm + L_RR + t * 4) = rsqrtf(s2 * (1.0f / DIM) + 1e-6f);
    }
    // ---- Q^T = wq^T * x1^T -> QPAD
    #pragma unroll
    for (int i = 0; i < 2; ++i) {
        const int mt = w, qt = i;
        f16v qa = (f16v)0.0f;
        #pragma unroll
        for (int s = 0; s < 16; ++s) {
            const s8v a  = *(const s8v*)(wqt + (mt * 16 + s) * 1024 + lane * 16);
            const s8v bb = *(const s8v*)(sm + L_X1PK + (qt * 16 + s) * 1024 + lane * 16);
            qa = MFMA32(a, bb, qa);
        }
        const int q = qt * 32 + l31;
        #pragma unroll
        for (int g = 0; g < 4; ++g) {
            const int d0 = 32 * mt + 8 * g + 4 * lh;
            u2v pk;
            pk.x = f2bf2(qa[4 * g + 0], qa[4 * g + 1]);
            pk.y = f2bf2(qa[4 * g + 2], qa[4 * g + 3]);
            *(u2v*)(sm + L_QPAD + q * 520 + d0 * 2) = pk;
        }
    }
    __syncthreads();
    // ---- Q B-frags into regs
    s8v qf[16];
    {
        const char* qbase = sm + L_QPAD + (qh * 32 + l31) * 520 + lh * 16;
        #pragma unroll
        for (int s = 0; s < 16; ++s) {
            S8U u;
            u.h[0] = *(const s4v*)(qbase + s * 32);
            u.h[1] = *(const s4v*)(qbase + s * 32 + 8);
            qf[s] = u.v;
        }
    }
    stage64(kpk, L_K);
    __syncthreads();   // drain K(0); QPAD reads complete

    f16v oacc0 = (f16v)0.0f, oacc1 = (f16v)0.0f;
    float lsum = 0.0f;

    // ---- main loop: 32 tiles of 128 keys
    for (int tile = 0; tile < 32; ++tile) {
        stage64(vpk + (size_t)tile * 65536, L_V);
        f16v sacc = (f16v)0.0f;
        #pragma unroll
        for (int s = 0; s < 16; ++s) {
            const s8v a = *(const s8v*)(sm + L_K
                + ((kh >> 1) * 32 + 2 * s + (kh & 1)) * 1024 + lane * 16);
            sacc = MFMA32(a, qf[s], sacc);
        }
        #pragma unroll
        for (int g = 0; g < 4; ++g) {
            const float p0 = __expf(sacc[4 * g + 0] * 0.0625f);
            const float p1 = __expf(sacc[4 * g + 1] * 0.0625f);
            const float p2 = __expf(sacc[4 * g + 2] * 0.0625f);
            const float p3 = __expf(sacc[4 * g + 3] * 0.0625f);
            lsum += (p0 + p1) + (p2 + p3);
            const int keyo = 32 * kh + 8 * g + 4 * lh;
            const int kc = keyo >> 4, ko = keyo & 15;
            u2v pk; pk.x = f2bf2(p0, p1); pk.y = f2bf2(p2, p3);
            *(u2v*)(sm + L_P + (qh * 8 + kc) * 1024
                    + (l31 + 32 * (ko >> 3)) * 16 + (ko & 7) * 2) = pk;
        }
        __syncthreads();   // barrier A: drains V(tile); P visible; K free
        if (tile < 31) stage64(kpk + (size_t)(tile + 1) * 65536, L_K);
        s8v pf[8];
        #pragma unroll
        for (int kc = 0; kc < 8; ++kc)
            pf[kc] = *(const s8v*)(sm + L_P + (qp * 8 + kc) * 1024 + lane * 16);
        #pragma unroll
        for (int kc = 0; kc < 8; ++kc) {
            const int sub = (kc >> 2) * 32, k3 = kc & 3;
            const s8v a0 = *(const s8v*)(sm + L_V + (sub + 4 * (2 * dpair) + k3) * 1024 + lane * 16);
            const s8v a1 = *(const s8v*)(sm + L_V + (sub + 4 * (2 * dpair + 1) + k3) * 1024 + lane * 16);
            oacc0 = MFMA32(a0, pf[kc], oacc0);
            oacc1 = MFMA32(a1, pf[kc], oacc1);
        }
        __syncthreads();   // barrier B: drains K(tile+1); V/P free
    }

    // ---- softmax denominators
    *(float*)(sm + L_LP + ((w * 2 + lh) * 32 + l31) * 4) = lsum;
    __syncthreads();
    if (t < 64) {
        const int qh_ = t >> 5, c = t & 31;
        const float* lp = (const float*)(sm + L_LP);
        float l = 0.f;
        #pragma unroll
        for (int k2 = 0; k2 < 4; ++k2)
            l += lp[((k2 * 2 + qh_) * 2 + 0) * 32 + c]
               + lp[((k2 * 2 + qh_) * 2 + 1) * 32 + c];
        *(float*)(sm + L_LINV + t * 4) = 1.0f / l;
    }
    __syncthreads();
    // ---- pack Ohat = O/l into OBUF
    {
        const float li = *(const float*)(sm + L_LINV + (qp * 32 + l31) * 4);
        #pragma unroll
        for (int half = 0; half < 2; ++half) {
            const f16v acc = half ? oacc1 : oacc0;
            const int dc = 2 * dpair + half;
            #pragma unroll
            for (int g = 0; g < 4; ++g) {
                const int d0 = dc * 32 + 8 * g + 4 * lh;
                u2v pk;
                pk.x = f2bf2(acc[4 * g + 0] * li, acc[4 * g + 1] * li);
                pk.y = f2bf2(acc[4 * g + 2] * li, acc[4 * g + 3] * li);
                *(u2v*)(sm + L_OBUF + (qp * 16 + (d0 >> 4)) * 1024
                        + (l31 + 32 * ((d0 >> 3) & 1)) * 16 + (d0 & 7) * 2) = pk;
            }
        }
    }
    // ---- rebuild x1 frags
    #pragma unroll
    for (int i = 0; i < 4; ++i) {
        const int c = t + 512 * i;
        const int q = c >> 5, d0 = (c & 31) * 8;
        const float4 a = *(const float4*)(x1 + (size_t)(qb + q) * DIM + d0);
        const float4 bb = *(const float4*)(x1 + (size_t)(qb + q) * DIM + d0 + 4);
        u4v pk;
        pk.x = f2bf2(a.x, a.y); pk.y = f2bf2(a.z, a.w);
        pk.z = f2bf2(bb.x, bb.y); pk.w = f2bf2(bb.z, bb.w);
        *(u4v*)(sm + L_X1PK2 + ((q >> 5) * 16 + (d0 >> 4)) * 1024
                + ((q & 31) + 32 * ((d0 >> 3) & 1)) * 16) = pk;
    }
    __syncthreads();
    // ---- combine + write out
    const float gw0 = wsf[WS_GATE + 0], gw1 = wsf[WS_GATE + 1];
    const float ginv = wsf[WS_GATE + 4], gcx1 = wsf[WS_GATE + 5];
    #pragma unroll
    for (int i = 0; i < 2; ++i) {
        const int mt = w, qt = i;
        f16v ea = (f16v)0.0f, sa = (f16v)0.0f;
        for (int s = 0; s < 16; ++s) {
            const s8v awo = *(const s8v*)(wot + (mt * 16 + s) * 1024 + lane * 16);
            const s8v aw1 = *(const s8v*)(w1t + (mt * 16 + s) * 1024 + lane * 16);
            const s8v bo = *(const s8v*)(sm + L_OBUF + (qt * 16 + s) * 1024 + lane * 16);
            const s8v bx = *(const s8v*)(sm + L_X1PK2 + (qt * 16 + s) * 1024 + lane * 16);
            ea = MFMA32(awo, bo, ea);
            sa = MFMA32(aw1, bx, sa);
        }
        const int q = qt * 32 + l31;
        const float rrq = *(const float*)(sm + L_RR + q * 4);
        #pragma unroll
        for (int g = 0; g < 4; ++g) {
            const int d0 = 32 * mt + 8 * g + 4 * lh;
            const float4 cv = *(const float4*)(sm + L_CVL + d0 * 4);
            const float4 bb = *(const float4*)(b1 + d0);
            const float4 xx = *(const float4*)(x1 + (size_t)(qb + q) * DIM + d0);
            float ev0 = sa[4 * g + 0] * rrq + bb.x; ev0 = (ev0 > 0.f) ? ev0 : expm1f(ev0);
            float ev1 = sa[4 * g + 1] * rrq + bb.y; ev1 = (ev1 > 0.f) ? ev1 : expm1f(ev1);
            float ev2 = sa[4 * g + 2] * rrq + bb.z; ev2 = (ev2 > 0.f) ? ev2 : expm1f(ev2);
            float ev3 = sa[4 * g + 3] * rrq + bb.w; ev3 = (ev3 > 0.f) ? ev3 : expm1f(ev3);
            float4 o;
            o.x = ginv * (gcx1 * xx.x + gw0 * ea[4 * g + 0] + gw1 * ev0 + cv.x);
            o.y = ginv * (gcx1 * xx.y + gw0 * ea[4 * g + 1] + gw1 * ev1 + cv.y);
            o.z = ginv * (gcx1 * xx.z + gw0 * ea[4 * g + 2] + gw1 * ev2 + cv.z);
            o.w = ginv * (gcx1 * xx.w + gw0 * ea[4 * g + 3] + gw1 * ev3 + cv.w);
            *(float4*)(out + (size_t)(qb + q) * DIM + d0) = o;
        }
    }
}

extern "C" void kernel_launch(void* const* d_in, const int* in_sizes, int n_in,
                              void* d_out, int out_size, void* d_ws, size_t ws_size,
                              hipStream_t stream)
{
    (void)in_sizes; (void)n_in; (void)out_size; (void)ws_size;
    const float* x1    = (const float*)d_in[0];
    const float* x2    = (const float*)d_in[1];
    const float* sim   = (const float*)d_in[2];
    const float* gates = (const float*)d_in[3];
    const float* g1    = (const float*)d_in[4];
    const float* g2    = (const float*)d_in[5];
    const float* w1m   = (const float*)d_in[6];
    const float* b1    = (const float*)d_in[7];
    const float* w2m   = (const float*)d_in[8];
    const float* b2    = (const float*)d_in[9];
    const float* wq    = (const float*)d_in[10];
    const float* wk    = (const float*)d_in[11];
    const float* wv    = (const float*)d_in[12];
    const float* wo    = (const float*)d_in[13];
    const float* va    = (const float*)d_in[14];
    const float* ua    = (const float*)d_in[15];
    const float* wa    = (const float*)d_in[16];
    const float* wf    = (const float*)d_in[17];
    float* ws  = (float*)d_ws;
    float* out = (float*)d_out;

    hipMemsetAsync(ws + WS_ACC, 0, 1056 * sizeof(float), stream);
    hipLaunchKernelGGL(k_pre, dim3(544), dim3(256), 0, stream,
                       x1, x2, wq, wo, w1m, wk, wv, w2m, va, ua, g1, g2, ws);
    hipLaunchKernelGGL(k_mid, dim3(129), dim3(512), 0, stream,
                       x2, b2, wa, sim, gates, ws);
    hipLaunchKernelGGL(k_flash, dim3(N1 / 64), dim3(512), SMEM_BYTES, stream,
                       x1, b1, wf, ws, out);
}

// Round 7
// 228.928 us; speedup vs baseline: 2.9694x; 1.0968x over previous
//
#include <hip/hip_runtime.h>
#include <math.h>

#define N1 16384
#define N2 4096
#define DIM 256
#define ATT 128

typedef unsigned int uint32;
typedef __attribute__((ext_vector_type(4))) short s4v;
typedef __attribute__((ext_vector_type(8))) short s8v;
typedef __attribute__((ext_vector_type(16))) float f16v;
typedef __attribute__((ext_vector_type(2))) uint32 u2v;
typedef __attribute__((ext_vector_type(4))) uint32 u4v;

union S8U { s8v v; s4v h[2]; };

#define AS1C const __attribute__((address_space(1)))
#define AS3 __attribute__((address_space(3)))

// ---- workspace layout (float offsets) ----
#define WS_KPK 0              // K frag-packed fp8 e4m3 [4096*256] = 1MB
#define WS_VPK 262144         // V^T frag-packed fp8
#define WS_WQT 524288         // packed bf16 weight frags, 128KB each (256x256)
#define WS_WOT 557056
#define WS_W1T 589824
#define WS_WKT 622592
#define WS_WVT 655360
#define WS_W2T 688128
#define WS_VAT 720896         // 64KB (256x128)
#define WS_UAT 737280
#define WS_ACC 753664         // zeroed region (1056 floats)
#define WS_COLSUM1 (WS_ACC)
#define WS_COLSUM2 (WS_ACC+256)
#define WS_S2SUM  (WS_ACC+512)
#define WS_CVRAW  (WS_ACC+768)      // pooledU @ wf (unnormalized)
#define WS_SUME   (WS_ACC+1024)
#define WS_GATE   (WS_ACC+1040)     // [8]: w0,w1,w2,w3,inv_ns,cx1

// ---- flash LDS layout (bytes): K 32K | V 32K | P 8K | misc ----
#define L_K    0
#define L_V    32768
#define L_P    65536
#define L_LP   73728
#define L_LINV 75776
#define L_RRS  76032
#define L_RR   76288
#define L_CVL  76544
#define L_X1PK  0          // prologue alias (K region, 32 KB, bf16 x1 frags)
#define L_QPAD  32768      // prologue alias (V region; 64*264 = 16.9 KB, fp8)
#define L_OBUF  0          // epilogue alias (K region, 32 KB, bf16 Ohat frags)
#define L_X1PK2 32768      // epilogue alias (V region, 32 KB, bf16 x1 frags)
#define SMEM_BYTES 77568

__device__ __forceinline__ uint32 f2bf1(float f) {
    uint32 u = __float_as_uint(f);
    return (u + 0x7fffu + ((u >> 16) & 1u)) >> 16;
}
__device__ __forceinline__ uint32 f2bf2(float lo, float hi) {
    return f2bf1(lo) | (f2bf1(hi) << 16);
}
__device__ __forceinline__ uint32 f2fp8x4(float a, float b, float c, float d) {
    uint32 r = __builtin_amdgcn_cvt_pk_fp8_f32(a, b, 0, 0);
    r = __builtin_amdgcn_cvt_pk_fp8_f32(c, d, r, 1);
    return r;
}
#define MFMA32(a, b, c) __builtin_amdgcn_mfma_f32_32x32x16_bf16((a), (b), (c), 0, 0, 0)
#define MFMA8(a, b, c)  __builtin_amdgcn_mfma_f32_32x32x16_fp8_fp8((a), (b), (c), 0, 0, 0)

// ============ k_pre: wpack (blocks 0..223) | colsum1 (224..479) | colsum2 (480..543)
__global__ __launch_bounds__(256) void k_pre(const float* __restrict__ x1,
    const float* __restrict__ x2,
    const float* __restrict__ wq, const float* __restrict__ wo,
    const float* __restrict__ snn_w1, const float* __restrict__ wk,
    const float* __restrict__ wv, const float* __restrict__ snn_w2,
    const float* __restrict__ va, const float* __restrict__ ua,
    const float* __restrict__ g1, const float* __restrict__ g2,
    float* __restrict__ ws)
{
    const int b = blockIdx.x;
    const int t = threadIdx.x;
    if (b < 224) {
        int mat, chunk, ncols;
        if (b < 192) { mat = b >> 5; chunk = b & 31; ncols = 256; }
        else { mat = 6 + ((b - 192) >> 4); chunk = (b - 192) & 15; ncols = 128; }
        const float* W;
        int dstoff;
        switch (mat) {
            case 0: W = wq;     dstoff = WS_WQT; break;
            case 1: W = wo;     dstoff = WS_WOT; break;
            case 2: W = snn_w1; dstoff = WS_W1T; break;
            case 3: W = wk;     dstoff = WS_WKT; break;
            case 4: W = wv;     dstoff = WS_WVT; break;
            case 5: W = snn_w2; dstoff = WS_W2T; break;
            case 6: W = va;     dstoff = WS_VAT; break;
            default: W = ua;    dstoff = WS_UAT; break;
        }
        unsigned short* dst = (unsigned short*)(ws + dstoff);
        const int e0 = chunk * 2048 + t * 8;
        const int k = (ncols == 256) ? (e0 >> 8) : (e0 >> 7);
        const int n0 = (ncols == 256) ? (e0 & 255) : (e0 & 127);
        const float4 v0 = *(const float4*)(W + k * ncols + n0);
        const float4 v1 = *(const float4*)(W + k * ncols + n0 + 4);
        const float sc = (mat == 2) ? g1[k] : ((mat == 5) ? g2[k] : 1.0f);
        float vals[8] = {v0.x, v0.y, v0.z, v0.w, v1.x, v1.y, v1.z, v1.w};
        const unsigned int sbase = (unsigned int)(k >> 4) * 512u
            + 32u * ((k >> 3) & 1) * 8u + (k & 7);
        #pragma unroll
        for (int jj = 0; jj < 8; ++jj) {
            const int n = n0 + jj;
            unsigned int off = (unsigned int)(n >> 5) * 16u * 512u + sbase
                             + (unsigned int)(n & 31) * 8u;
            dst[off] = (unsigned short)f2bf1(vals[jj] * sc);
        }
    } else if (b < 480) {
        const int rbase = (b - 224) * 64;
        float acc = 0.f;
        for (int r = 0; r < 64; ++r) acc += x1[(size_t)(rbase + r) * DIM + t];
        atomicAdd(&ws[WS_COLSUM1 + t], acc);
    } else {
        const int rbase = (b - 480) * 64;
        float acc = 0.f;
        for (int r = 0; r < 64; ++r) acc += x2[(size_t)(rbase + r) * DIM + t];
        atomicAdd(&ws[WS_COLSUM2 + t], acc);
    }
}

// ============ k_mid: x2prep (fp8 K/V pack) + DAMISL/pool partials (0..127) | gate (128)
__global__ __launch_bounds__(512) void k_mid(const float* __restrict__ x2,
    const float* __restrict__ b2, const float* __restrict__ wa,
    const float* __restrict__ sim, const float* __restrict__ gates,
    const float* __restrict__ wf,
    float* __restrict__ ws)
{
    __shared__ char xps[16384];     // x2^T bf16 frags
    __shared__ float rrs[32];
    __shared__ float dlp[128];
    __shared__ float expE[32];
    __shared__ float acc9[9];
    __shared__ float pph[512];
    __shared__ float pbv[256];
    const int t = threadIdx.x;
    const int w = t >> 6;
    const int lane = t & 63;
    const int l31 = lane & 31;
    const int lh = lane >> 5;
    const int b = blockIdx.x;

    if (b == 128) {
        // ---- gate: cosine scores + top-2 + threshold
        if (t < 9) acc9[t] = 0.f;
        __syncthreads();
        float fv = 0.f;
        if (t < 256)
            fv = 0.5f * (ws[WS_COLSUM1 + t] * (1.0f / N1)
                       + ws[WS_COLSUM2 + t] * (1.0f / N2));
        {
            float p = fv * fv;
            #pragma unroll
            for (int o = 32; o > 0; o >>= 1) p += __shfl_xor(p, o);
            if (lane == 0) atomicAdd(&acc9[0], p);
        }
        #pragma unroll
        for (int e = 0; e < 4; ++e) {
            const float sv = (t < 256) ? sim[e * DIM + t] : 0.f;
            float pn = sv * sv, pd = sv * fv;
            #pragma unroll
            for (int o = 32; o > 0; o >>= 1) { pn += __shfl_xor(pn, o); pd += __shfl_xor(pd, o); }
            if (lane == 0) { atomicAdd(&acc9[1 + e], pn); atomicAdd(&acc9[5 + e], pd); }
        }
        __syncthreads();
        if (t == 0) {
            const float rsqf = rsqrtf(acc9[0] + 1e-8f);
            float sc[4];
            #pragma unroll
            for (int e = 0; e < 4; ++e)
                sc[e] = acc9[5 + e] * rsqf * rsqrtf(acc9[1 + e] + 1e-8f);
            float a = -1e30f, bb = -1e30f;
            #pragma unroll
            for (int e = 0; e < 4; ++e) {
                const float v = sc[e];
                if (v > a) { bb = a; a = v; } else if (v > bb) { bb = v; }
            }
            float wv_[4]; int ns = 0;
            #pragma unroll
            for (int e = 0; e < 4; ++e) {
                const bool keep = (sc[e] >= bb) && (sc[e] > gates[e]);
                wv_[e] = keep ? sc[e] : 0.f;
                if (wv_[e] > 0.f) ns++;
            }
            if (ns < 1) ns = 1;
            ws[WS_GATE + 0] = wv_[0]; ws[WS_GATE + 1] = wv_[1];
            ws[WS_GATE + 2] = wv_[2]; ws[WS_GATE + 3] = wv_[3];
            ws[WS_GATE + 4] = 1.0f / (float)ns;
            ws[WS_GATE + 5] = wv_[0] + wv_[2] + wv_[3];
        }
        return;
    }

    const int tb = b * 32;
    unsigned char* kpk = (unsigned char*)(ws + WS_KPK);
    unsigned char* vpk = (unsigned char*)(ws + WS_VPK);
    const char* wsb = (const char*)ws;
    const char* wkt = wsb + (size_t)WS_WKT * 4;
    const char* wvt = wsb + (size_t)WS_WVT * 4;
    const char* w2t = wsb + (size_t)WS_W2T * 4;
    const char* vat = wsb + (size_t)WS_VAT * 4;
    const char* uat = wsb + (size_t)WS_UAT * 4;

    // ---- load + pack x2 tile (bf16 frags), rms partials
    #pragma unroll
    for (int i = 0; i < 2; ++i) {
        const int c = t + 512 * i;
        const int tk = c >> 5, d0 = (c & 31) * 8;
        const float4 a = *(const float4*)(x2 + (size_t)(tb + tk) * DIM + d0);
        const float4 bb = *(const float4*)(x2 + (size_t)(tb + tk) * DIM + d0 + 4);
        float ss = a.x*a.x + a.y*a.y + a.z*a.z + a.w*a.w
                 + bb.x*bb.x + bb.y*bb.y + bb.z*bb.z + bb.w*bb.w;
        #pragma unroll
        for (int o = 16; o > 0; o >>= 1) ss += __shfl_down(ss, o, 32);
        if ((t & 31) == 0) rrs[tk] = ss;
        u4v pk;
        pk.x = f2bf2(a.x, a.y); pk.y = f2bf2(a.z, a.w);
        pk.z = f2bf2(bb.x, bb.y); pk.w = f2bf2(bb.z, bb.w);
        *(u4v*)(xps + (d0 >> 4) * 1024 + (tk + 32 * ((d0 >> 3) & 1)) * 16) = pk;
    }
    __syncthreads();

    { // K^T = wk^T * x2^T -> fp8 frag pack
        f16v kacc = (f16v)0.0f;
        #pragma unroll
        for (int s = 0; s < 16; ++s) {
            const s8v a = *(const s8v*)(wkt + (w * 16 + s) * 1024 + lane * 16);
            const s8v bb = *(const s8v*)(xps + s * 1024 + lane * 16);
            kacc = MFMA32(a, bb, kacc);
        }
        #pragma unroll
        for (int g = 0; g < 4; ++g) {
            const unsigned int chunkK =
                (unsigned int)((b >> 1) * 32 + 2 * (2 * w + (g >> 1)) + (b & 1));
            const unsigned int off = chunkK * 512u
                + (unsigned int)(l31 + 32 * (g & 1)) * 8u + 4u * lh;
            *(uint32*)(kpk + off) = f2fp8x4(kacc[4*g+0], kacc[4*g+1], kacc[4*g+2], kacc[4*g+3]);
        }
    }
    { // V = x2 * wv -> fp8 frag pack
        f16v vacc = (f16v)0.0f;
        #pragma unroll
        for (int s = 0; s < 16; ++s) {
            const s8v a = *(const s8v*)(xps + s * 1024 + lane * 16);
            const s8v bb = *(const s8v*)(wvt + (w * 16 + s) * 1024 + lane * 16);
            vacc = MFMA32(a, bb, vacc);
        }
        #pragma unroll
        for (int g = 0; g < 4; ++g) {
            const unsigned int chunkV =
                (unsigned int)((b >> 1) * 32 + 4 * w + 2 * (b & 1) + (g >> 1));
            const unsigned int off = chunkV * 512u
                + (unsigned int)(l31 + 32 * (g & 1)) * 8u + 4u * lh;
            *(uint32*)(vpk + off) = f2fp8x4(vacc[4*g+0], vacc[4*g+1], vacc[4*g+2], vacc[4*g+3]);
        }
    }
    { // SNN elu colsum -> S2SUM
        f16v sacc = (f16v)0.0f;
        #pragma unroll
        for (int s = 0; s < 16; ++s) {
            const s8v a = *(const s8v*)(w2t + (w * 16 + s) * 1024 + lane * 16);
            const s8v bb = *(const s8v*)(xps + s * 1024 + lane * 16);
            sacc = MFMA32(a, bb, sacc);
        }
        const float rrl = rsqrtf(rrs[l31] * (1.0f / DIM) + 1e-6f);
        #pragma unroll
        for (int g = 0; g < 4; ++g) {
            const float4 bb = *(const float4*)(b2 + 32 * w + 8 * g + 4 * lh);
            #pragma unroll
            for (int jj = 0; jj < 4; ++jj) {
                float v = sacc[4 * g + jj] * rrl + ((const float*)&bb)[jj];
                v = (v > 0.f) ? v : expm1f(v);
                v += __shfl_xor(v, 16); v += __shfl_xor(v, 8);
                v += __shfl_xor(v, 4);  v += __shfl_xor(v, 2);
                v += __shfl_xor(v, 1);
                if (l31 == 0)
                    atomicAdd(&ws[WS_S2SUM + 32 * w + 8 * g + 4 * lh + jj], v);
            }
        }
    }
    if (w < 4) { // DAMISL logit partials over ATT chunk w
        f16v hv = (f16v)0.0f, hu = (f16v)0.0f;
        #pragma unroll
        for (int s = 0; s < 16; ++s) {
            const s8v bb = *(const s8v*)(xps + s * 1024 + lane * 16);
            const s8v a1 = *(const s8v*)(vat + (w * 16 + s) * 1024 + lane * 16);
            const s8v a2 = *(const s8v*)(uat + (w * 16 + s) * 1024 + lane * 16);
            hv = MFMA32(a1, bb, hv);
            hu = MFMA32(a2, bb, hu);
        }
        float acc = 0.f;
        #pragma unroll
        for (int g = 0; g < 4; ++g) {
            const float4 w4 = *(const float4*)(wa + 32 * w + 8 * g + 4 * lh);
            #pragma unroll
            for (int jj = 0; jj < 4; ++jj) {
                acc += tanhf(hv[4 * g + jj])
                     * (1.0f / (1.0f + __expf(-hu[4 * g + jj])))
                     * ((const float*)&w4)[jj];
            }
        }
        acc += __shfl_xor(acc, 32);
        if (lh == 0) dlp[w * 32 + l31] = acc;
    }
    __syncthreads();
    if (t < 32) { // max-free exp of token logits + sumE partial
        const float lg = dlp[t] + dlp[32 + t] + dlp[64 + t] + dlp[96 + t];
        const float e_ = __expf(lg);
        expE[t] = e_;
        float s = e_;
        #pragma unroll
        for (int o = 16; o > 0; o >>= 1) s += __shfl_xor(s, o);
        if (t == 0) atomicAdd(&ws[WS_SUME], s);
    }
    __syncthreads();
    { // pooledU block-partial
        const int d = t & 255, half = t >> 8;
        const int r0 = half * 16;
        float acc = 0.f;
        #pragma unroll
        for (int r = 0; r < 16; ++r)
            acc = fmaf(expE[r0 + r], x2[(size_t)(tb + r0 + r) * DIM + d], acc);
        pph[t] = acc;
    }
    __syncthreads();
    if (t < 256) pbv[t] = pph[t] + pph[t + 256];
    __syncthreads();
    { // cvraw partial: pooledU_b @ wf
        const int o = t & 255, h2 = t >> 8;
        float ca = 0.f;
        #pragma unroll 4
        for (int d2 = h2 * 128; d2 < h2 * 128 + 128; ++d2)
            ca = fmaf(pbv[d2], wf[d2 * DIM + o], ca);
        pph[t] = ca;
    }
    __syncthreads();
    if (t < 256) atomicAdd(&ws[WS_CVRAW + t], pph[t] + pph[t + 256]);
}

// ============ k_flash: fp8 MFMA flash attention + fused bf16 epilogue
__global__ __launch_bounds__(512, 2) void k_flash(
    const float* __restrict__ x1, const float* __restrict__ b1,
    const float* __restrict__ wsf, float* __restrict__ out)
{
    extern __shared__ char sm[];
    const int t = threadIdx.x;
    const int w = t >> 6;
    const int lane = t & 63;
    const int l31 = lane & 31;
    const int lh = lane >> 5;
    const int qb = blockIdx.x * 64;
    const int kh = w >> 1, qh = w & 1;     // S-phase roles
    const int qp = w & 1, dpair = w >> 1;  // PV-phase roles
    const char* wsb = (const char*)wsf;
    const char* kpk = wsb + (size_t)WS_KPK * 4;
    const char* vpk = wsb + (size_t)WS_VPK * 4;
    const char* wqt = wsb + (size_t)WS_WQT * 4;
    const char* wot = wsb + (size_t)WS_WOT * 4;
    const char* w1t = wsb + (size_t)WS_W1T * 4;

    auto stage32 = [&](const char* gbase, int ldsoff) {
        #pragma unroll
        for (int i = 0; i < 4; ++i) {
            const int c = w * 4 + i;
            __builtin_amdgcn_global_load_lds(
                (AS1C uint32*)(gbase + c * 1024 + lane * 16),
                (AS3 uint32*)(sm + ldsoff + c * 1024), 16, 0, 0);
        }
    };

    // ---- cvec from precomputed partials
    if (t < 256) {
        const float se = wsf[WS_SUME];
        ((float*)(sm + L_CVL))[t] =
            wsf[WS_GATE + 1] * (wsf[WS_S2SUM + t] * (1.0f / N2))
          + wsf[WS_GATE + 2] * (wsf[WS_CVRAW + t] / se);
    }

    // ---- prologue: x1 bf16 frags + rms partials
    #pragma unroll
    for (int i = 0; i < 4; ++i) {
        const int c = t + 512 * i;
        const int q = c >> 5, d0 = (c & 31) * 8;
        const float4 a = *(const float4*)(x1 + (size_t)(qb + q) * DIM + d0);
        const float4 bb = *(const float4*)(x1 + (size_t)(qb + q) * DIM + d0 + 4);
        float ss = a.x*a.x + a.y*a.y + a.z*a.z + a.w*a.w
                 + bb.x*bb.x + bb.y*bb.y + bb.z*bb.z + bb.w*bb.w;
        #pragma unroll
        for (int o = 16; o > 0; o >>= 1) ss += __shfl_down(ss, o, 32);
        if ((t & 31) == 0) *(float*)(sm + L_RRS + q * 4) = ss;
        u4v pk;
        pk.x = f2bf2(a.x, a.y); pk.y = f2bf2(a.z, a.w);
        pk.z = f2bf2(bb.x, bb.y); pk.w = f2bf2(bb.z, bb.w);
        *(u4v*)(sm + L_X1PK + ((q >> 5) * 16 + (d0 >> 4)) * 1024
                + ((q & 31) + 32 * ((d0 >> 3) & 1)) * 16) = pk;
    }
    __syncthreads();
    if (t < 64) {
        const float s2 = *(const float*)(sm + L_RRS + t * 4);
        *(float*)(sm + L_RR + t * 4) = rsqrtf(s2 * (1.0f / DIM) + 1e-6f);
    }
    // ---- Q^T = wq^T * x1^T -> QPAD [q][d] fp8 (row stride 264 B)
    #pragma unroll
    for (int i = 0; i < 2; ++i) {
        const int mt = w, qt = i;
        f16v qa = (f16v)0.0f;
        #pragma unroll
        for (int s = 0; s < 16; ++s) {
            const s8v a  = *(const s8v*)(wqt + (mt * 16 + s) * 1024 + lane * 16);
            const s8v bb = *(const s8v*)(sm + L_X1PK + (qt * 16 + s) * 1024 + lane * 16);
            qa = MFMA32(a, bb, qa);
        }
        const int q = qt * 32 + l31;
        #pragma unroll
        for (int g = 0; g < 4; ++g) {
            const int d0 = 32 * mt + 8 * g + 4 * lh;
            *(uint32*)(sm + L_QPAD + q * 264 + d0) =
                f2fp8x4(qa[4*g+0], qa[4*g+1], qa[4*g+2], qa[4*g+3]);
        }
    }
    __syncthreads();
    // ---- Q B-frags (fp8, 8 B/lane) into regs
    long qf[16];
    {
        const char* qbase = sm + L_QPAD + (qh * 32 + l31) * 264 + lh * 8;
        #pragma unroll
        for (int s = 0; s < 16; ++s)
            qf[s] = *(const long*)(qbase + s * 16);
    }
    stage32(kpk, L_K);
    __syncthreads();   // drain K(0); QPAD reads complete

    f16v oacc0 = (f16v)0.0f, oacc1 = (f16v)0.0f;
    float lsum = 0.0f;

    // ---- main loop: 32 tiles of 128 keys (fp8 core)
    for (int tile = 0; tile < 32; ++tile) {
        stage32(vpk + (size_t)tile * 32768, L_V);
        // S^T = K(kh quarter) * Q^T(qh half)
        f16v sacc = (f16v)0.0f;
        #pragma unroll
        for (int s = 0; s < 16; ++s) {
            const long a = *(const long*)(sm + L_K
                + ((kh >> 1) * 32 + 2 * s + (kh & 1)) * 512 + lane * 8);
            sacc = MFMA8(a, qf[s], sacc);
        }
        // exp (max-free), pack P -> fp8 B-frags
        #pragma unroll
        for (int g = 0; g < 4; ++g) {
            const float p0 = __expf(sacc[4 * g + 0] * 0.0625f);
            const float p1 = __expf(sacc[4 * g + 1] * 0.0625f);
            const float p2 = __expf(sacc[4 * g + 2] * 0.0625f);
            const float p3 = __expf(sacc[4 * g + 3] * 0.0625f);
            lsum += (p0 + p1) + (p2 + p3);
            const int keyo = 32 * kh + 8 * g + 4 * lh;
            const int kc = keyo >> 4, ko = keyo & 15;
            *(uint32*)(sm + L_P + (qh * 8 + kc) * 512
                       + (l31 + 32 * (ko >> 3)) * 8 + (ko & 7)) =
                f2fp8x4(p0, p1, p2, p3);
        }
        __syncthreads();   // barrier A: drains V(tile); P visible; K free
        if (tile < 31) stage32(kpk + (size_t)(tile + 1) * 32768, L_K);
        // O^T += V^T * P^T
        long pf[8];
        #pragma unroll
        for (int kc = 0; kc < 8; ++kc)
            pf[kc] = *(const long*)(sm + L_P + (qp * 8 + kc) * 512 + lane * 8);
        #pragma unroll
        for (int kc = 0; kc < 8; ++kc) {
            const int sub = (kc >> 2) * 32, k3 = kc & 3;
            const long a0 = *(const long*)(sm + L_V + (sub + 4 * (2 * dpair) + k3) * 512 + lane * 8);
            const long a1 = *(const long*)(sm + L_V + (sub + 4 * (2 * dpair + 1) + k3) * 512 + lane * 8);
            oacc0 = MFMA8(a0, pf[kc], oacc0);
            oacc1 = MFMA8(a1, pf[kc], oacc1);
        }
        __syncthreads();   // barrier B: drains K(tile+1); V/P free
    }

    // ---- softmax denominators
    *(float*)(sm + L_LP + ((w * 2 + lh) * 32 + l31) * 4) = lsum;
    __syncthreads();
    if (t < 64) {
        const int qh_ = t >> 5, c = t & 31;
        const float* lp = (const float*)(sm + L_LP);
        float l = 0.f;
        #pragma unroll
        for (int k2 = 0; k2 < 4; ++k2)
            l += lp[((k2 * 2 + qh_) * 2 + 0) * 32 + c]
               + lp[((k2 * 2 + qh_) * 2 + 1) * 32 + c];
        *(float*)(sm + L_LINV + t * 4) = 1.0f / l;
    }
    __syncthreads();
    // ---- pack Ohat = O/l into OBUF (bf16 B-frags)
    {
        const float li = *(const float*)(sm + L_LINV + (qp * 32 + l31) * 4);
        #pragma unroll
        for (int half = 0; half < 2; ++half) {
            const f16v acc = half ? oacc1 : oacc0;
            const int dc = 2 * dpair + half;
            #pragma unroll
            for (int g = 0; g < 4; ++g) {
                const int d0 = dc * 32 + 8 * g + 4 * lh;
                u2v pk;
                pk.x = f2bf2(acc[4 * g + 0] * li, acc[4 * g + 1] * li);
                pk.y = f2bf2(acc[4 * g + 2] * li, acc[4 * g + 3] * li);
                *(u2v*)(sm + L_OBUF + (qp * 16 + (d0 >> 4)) * 1024
                        + (l31 + 32 * ((d0 >> 3) & 1)) * 16 + (d0 & 7) * 2) = pk;
            }
        }
    }
    // ---- rebuild x1 bf16 frags (epilogue)
    #pragma unroll
    for (int i = 0; i < 4; ++i) {
        const int c = t + 512 * i;
        const int q = c >> 5, d0 = (c & 31) * 8;
        const float4 a = *(const float4*)(x1 + (size_t)(qb + q) * DIM + d0);
        const float4 bb = *(const float4*)(x1 + (size_t)(qb + q) * DIM + d0 + 4);
        u4v pk;
        pk.x = f2bf2(a.x, a.y); pk.y = f2bf2(a.z, a.w);
        pk.z = f2bf2(bb.x, bb.y); pk.w = f2bf2(bb.z, bb.w);
        *(u4v*)(sm + L_X1PK2 + ((q >> 5) * 16 + (d0 >> 4)) * 1024
                + ((q & 31) + 32 * ((d0 >> 3) & 1)) * 16) = pk;
    }
    __syncthreads();
    // ---- combine: E0c^T = wo^T*Ohat^T ; S1^T = W1g^T*x1^T ; write out
    const float gw0 = wsf[WS_GATE + 0], gw1 = wsf[WS_GATE + 1];
    const float ginv = wsf[WS_GATE + 4], gcx1 = wsf[WS_GATE + 5];
    #pragma unroll
    for (int i = 0; i < 2; ++i) {
        const int mt = w, qt = i;
        f16v ea = (f16v)0.0f, sa = (f16v)0.0f;
        for (int s = 0; s < 16; ++s) {
            const s8v awo = *(const s8v*)(wot + (mt * 16 + s) * 1024 + lane * 16);
            const s8v aw1 = *(const s8v*)(w1t + (mt * 16 + s) * 1024 + lane * 16);
            const s8v bo = *(const s8v*)(sm + L_OBUF + (qt * 16 + s) * 1024 + lane * 16);
            const s8v bx = *(const s8v*)(sm + L_X1PK2 + (qt * 16 + s) * 1024 + lane * 16);
            ea = MFMA32(awo, bo, ea);
            sa = MFMA32(aw1, bx, sa);
        }
        const int q = qt * 32 + l31;
        const float rrq = *(const float*)(sm + L_RR + q * 4);
        #pragma unroll
        for (int g = 0; g < 4; ++g) {
            const int d0 = 32 * mt + 8 * g + 4 * lh;
            const float4 cv = *(const float4*)(sm + L_CVL + d0 * 4);
            const float4 bb = *(const float4*)(b1 + d0);
            const float4 xx = *(const float4*)(x1 + (size_t)(qb + q) * DIM + d0);
            float ev0 = sa[4 * g + 0] * rrq + bb.x; ev0 = (ev0 > 0.f) ? ev0 : expm1f(ev0);
            float ev1 = sa[4 * g + 1] * rrq + bb.y; ev1 = (ev1 > 0.f) ? ev1 : expm1f(ev1);
            float ev2 = sa[4 * g + 2] * rrq + bb.z; ev2 = (ev2 > 0.f) ? ev2 : expm1f(ev2);
            float ev3 = sa[4 * g + 3] * rrq + bb.w; ev3 = (ev3 > 0.f) ? ev3 : expm1f(ev3);
            float4 o;
            o.x = ginv * (gcx1 * xx.x + gw0 * ea[4 * g + 0] + gw1 * ev0 + cv.x);
            o.y = ginv * (gcx1 * xx.y + gw0 * ea[4 * g + 1] + gw1 * ev1 + cv.y);
            o.z = ginv * (gcx1 * xx.z + gw0 * ea[4 * g + 2] + gw1 * ev2 + cv.z);
            o.w = ginv * (gcx1 * xx.w + gw0 * ea[4 * g + 3] + gw1 * ev3 + cv.w);
            *(float4*)(out + (size_t)(qb + q) * DIM + d0) = o;
        }
    }
}

extern "C" void kernel_launch(void* const* d_in, const int* in_sizes, int n_in,
                              void* d_out, int out_size, void* d_ws, size_t ws_size,
                              hipStream_t stream)
{
    (void)in_sizes; (void)n_in; (void)out_size; (void)ws_size;
    const float* x1    = (const float*)d_in[0];
    const float* x2    = (const float*)d_in[1];
    const float* sim   = (const float*)d_in[2];
    const float* gates = (const float*)d_in[3];
    const float* g1    = (const float*)d_in[4];
    const float* g2    = (const float*)d_in[5];
    const float* w1m   = (const float*)d_in[6];
    const float* b1    = (const float*)d_in[7];
    const float* w2m   = (const float*)d_in[8];
    const float* b2    = (const float*)d_in[9];
    const float* wq    = (const float*)d_in[10];
    const float* wk    = (const float*)d_in[11];
    const float* wv    = (const float*)d_in[12];
    const float* wo    = (const float*)d_in[13];
    const float* va    = (const float*)d_in[14];
    const float* ua    = (const float*)d_in[15];
    const float* wa    = (const float*)d_in[16];
    const float* wf    = (const float*)d_in[17];
    float* ws  = (float*)d_ws;
    float* out = (float*)d_out;

    hipMemsetAsync(ws + WS_ACC, 0, 1056 * sizeof(float), stream);
    hipLaunchKernelGGL(k_pre, dim3(544), dim3(256), 0, stream,
                       x1, x2, wq, wo, w1m, wk, wv, w2m, va, ua, g1, g2, ws);
    hipLaunchKernelGGL(k_mid, dim3(129), dim3(512), 0, stream,
                       x2, b2, wa, sim, gates, wf, ws);
    hipLaunchKernelGGL(k_flash, dim3(N1 / 64), dim3(512), SMEM_BYTES, stream,
                       x1, b1, ws, out);
}